// Round 1
// baseline (779.353 us; speedup 1.0000x reference)
//
#include <hip/hip_runtime.h>
#include <cstddef>

#define AZ -999999.0f

typedef float  f32x4  __attribute__((ext_vector_type(4)));
typedef short  s16x8  __attribute__((ext_vector_type(8)));
typedef short  s16x4  __attribute__((ext_vector_type(4)));
typedef __bf16 bf16x8 __attribute__((ext_vector_type(8)));

__device__ __forceinline__ unsigned short f2bf(float f) {
    union { float f; unsigned u; } un; un.f = f;
    return (unsigned short)((un.u + 0x7FFFu + ((un.u >> 16) & 1u)) >> 16);
}

__device__ __forceinline__ f32x4 mfma16(s16x8 a, s16x8 b, f32x4 c) {
    return __builtin_amdgcn_mfma_f32_16x16x32_bf16(
        __builtin_bit_cast(bf16x8, a), __builtin_bit_cast(bf16x8, b), c, 0, 0, 0);
}

// ---- tiny setup kernels ------------------------------------------------
// B (K x 256, f32 row-major)  ->  BT (256 x K, bf16 row-major)
__global__ void transpose_cvt(const float* __restrict__ B,
                              unsigned short* __restrict__ BT, int K) {
    int idx = blockIdx.x * 256 + threadIdx.x;   // grid.x == K exactly
    int k = idx >> 8, n = idx & 255;
    BT[(size_t)n * K + k] = f2bf(B[idx]);
}

// per-edge packed mask metadata: pl | cl<<4 | op<<8 | oc<<9
__global__ void edge_meta_kernel(const int* __restrict__ pidx, const int* __restrict__ cidx,
                                 const int* __restrict__ tl, const int* __restrict__ obs,
                                 int* __restrict__ meta, int E) {
    int e = blockIdx.x * 256 + threadIdx.x;
    if (e < E) {
        int p = pidx[e], c = cidx[e];
        meta[e] = (tl[p] & 15) | ((tl[c] & 15) << 4) | ((obs[p] & 1) << 8) | ((obs[c] & 1) << 9);
    }
}

// ---- main GEMM ---------------------------------------------------------
// AMODE: 0 = A f32 row-major lda=768 (features)
//        1 = A bf16 row-major lda=256 (h1)
//        2 = A bf16 gathered: rows = h2[parent] (k<256) | h2[child] (k>=256)
// EPI:   0 = relu(acc+bias) -> bf16, ldc=256
//        1 = edge mask (meta) on acc+bias -> f32, ldc=256
template<int AMODE, int EPI>
__global__ __launch_bounds__(256) void gemm_kernel(
    const void* __restrict__ Aptr, const unsigned short* __restrict__ BT,
    const float* __restrict__ bias, void* __restrict__ outp,
    int M, int K,
    const int* __restrict__ parent_idx, const int* __restrict__ child_idx,
    const int* __restrict__ meta)
{
    // +8 pad: row stride 80B -> 16B aligned b128 reads, 2-way bank alias (free)
    __shared__ unsigned short As[128][40];
    __shared__ unsigned short Bs[128][40];
    const int tid = threadIdx.x;
    const int row0    = blockIdx.y * 128;
    const int colbase = blockIdx.x * 128;
    const int lane = tid & 63;
    const int wave = tid >> 6;
    const int wr = (wave >> 1) * 64, wc = (wave & 1) * 64;
    const int quad = lane >> 4, l16 = lane & 15;

    const f32x4 fz = {0.f, 0.f, 0.f, 0.f};
    f32x4 acc[4][4];
#pragma unroll
    for (int i = 0; i < 4; ++i)
#pragma unroll
        for (int j = 0; j < 4; ++j) acc[i][j] = fz;

    const int nkt = K >> 5;
    for (int kt = 0; kt < nkt; ++kt) {
        const int kbase = kt << 5;
        // stage B: 128 cols x 32 k, from pre-transposed bf16 BT
#pragma unroll
        for (int i = 0; i < 2; ++i) {
            int chunk = tid + i * 256;
            int n = chunk >> 2, c8 = (chunk & 3) << 3;
            s16x8 v = *(const s16x8*)&BT[(size_t)(colbase + n) * K + kbase + c8];
            *(s16x8*)&Bs[n][c8] = v;
        }
        // stage A
        if constexpr (AMODE == 0) {
            const float* A = (const float*)Aptr;
#pragma unroll
            for (int i = 0; i < 4; ++i) {
                int q = tid + i * 256;
                int row = q >> 3, c4 = (q & 7) << 2;
                int gr = row0 + row;
                f32x4 v = fz;
                if (gr < M) v = *(const f32x4*)&A[(size_t)gr * 768 + kbase + c4];
                s16x4 w;
                w[0] = (short)f2bf(v[0]); w[1] = (short)f2bf(v[1]);
                w[2] = (short)f2bf(v[2]); w[3] = (short)f2bf(v[3]);
                *(s16x4*)&As[row][c4] = w;
            }
        } else {
            const unsigned short* A = (const unsigned short*)Aptr;
#pragma unroll
            for (int i = 0; i < 2; ++i) {
                int chunk = tid + i * 256;
                int row = chunk >> 2, c8 = (chunk & 3) << 3;
                int gr = row0 + row;
                s16x8 v = {0, 0, 0, 0, 0, 0, 0, 0};
                if (gr < M) {
                    size_t src;
                    if constexpr (AMODE == 2) {
                        int node = (kbase < 256) ? parent_idx[gr] : child_idx[gr];
                        src = (size_t)node * 256 + (kbase & 255) + c8;
                    } else {
                        src = (size_t)gr * 256 + kbase + c8;
                    }
                    v = *(const s16x8*)&A[src];
                }
                *(s16x8*)&As[row][c8] = v;
            }
        }
        __syncthreads();
        s16x8 af[4], bf[4];
#pragma unroll
        for (int f = 0; f < 4; ++f) af[f] = *(const s16x8*)&As[wr + f * 16 + l16][quad << 3];
#pragma unroll
        for (int f = 0; f < 4; ++f) bf[f] = *(const s16x8*)&Bs[wc + f * 16 + l16][quad << 3];
#pragma unroll
        for (int fr = 0; fr < 4; ++fr)
#pragma unroll
            for (int fc = 0; fc < 4; ++fc)
                acc[fr][fc] = mfma16(af[fr], bf[fc], acc[fr][fc]);
        __syncthreads();
    }

    // epilogue. C/D layout (measured): col = lane&15, row = quad*4 + reg
    float bv[4];
#pragma unroll
    for (int fc = 0; fc < 4; ++fc) bv[fc] = bias[colbase + wc + fc * 16 + l16];

    if constexpr (EPI == 0) {
        unsigned short* out = (unsigned short*)outp;
#pragma unroll
        for (int fr = 0; fr < 4; ++fr) {
#pragma unroll
            for (int r = 0; r < 4; ++r) {
                int gr = row0 + wr + fr * 16 + quad * 4 + r;
                if (gr < M) {
#pragma unroll
                    for (int fc = 0; fc < 4; ++fc) {
                        float v = acc[fr][fc][r] + bv[fc];
                        v = v > 0.f ? v : 0.f;
                        out[(size_t)gr * 256 + colbase + wc + fc * 16 + l16] = f2bf(v);
                    }
                }
            }
        }
    } else {
        float* out = (float*)outp;
#pragma unroll
        for (int fr = 0; fr < 4; ++fr) {
#pragma unroll
            for (int r = 0; r < 4; ++r) {
                int e = row0 + wr + fr * 16 + quad * 4 + r;
                if (e < M) {
                    int m  = meta[e];
                    int pl = m & 15, cl = (m >> 4) & 15;
                    int op = (m >> 8) & 1, oc = (m >> 9) & 1;
#pragma unroll
                    for (int fc = 0; fc < 4; ++fc) {
                        int n = colbase + wc + fc * 16 + l16;
                        float v = acc[fr][fc][r] + bv[fc];
                        int rr = n >> 4, cc = n & 15;
                        if (op & oc)  v = (rr == pl && cc == cl) ? 0.0f : AZ;
                        else if (oc)  { if (rr != cl) v += AZ; }
                        else if (op)  { if (cc != pl) v += AZ; }
                        out[(size_t)e * 256 + n] = v;
                    }
                }
            }
        }
    }
}

// ---- unary: 16 nodes per wave via one MFMA column-tile -----------------
__global__ __launch_bounds__(256) void unary_kernel(
    const unsigned short* __restrict__ h2, const float* __restrict__ Wu,
    const float* __restrict__ bu, const int* __restrict__ tl,
    const int* __restrict__ obs, float* __restrict__ out, int N)
{
    __shared__ unsigned short WuT[16][272];   // 544B stride: 16B aligned, 4-way alias ok
    const int tid = threadIdx.x;
    {
        const f32x4* wrow = (const f32x4*)&Wu[tid * 16];  // thread t stages k-row t
        float tmp[16];
#pragma unroll
        for (int j = 0; j < 4; ++j) {
            f32x4 v = wrow[j];
            tmp[j * 4 + 0] = v[0]; tmp[j * 4 + 1] = v[1];
            tmp[j * 4 + 2] = v[2]; tmp[j * 4 + 3] = v[3];
        }
#pragma unroll
        for (int c = 0; c < 16; ++c) WuT[c][tid] = f2bf(tmp[c]);
    }
    __syncthreads();
    const int lane = tid & 63, wave = tid >> 6;
    const int quad = lane >> 4, col = lane & 15;
    const int n0 = blockIdx.x * 64 + wave * 16;
    int arow = n0 + col;
    if (arow > N - 1) arow = N - 1;               // clamp; stores are guarded
    f32x4 acc = {0.f, 0.f, 0.f, 0.f};
#pragma unroll
    for (int kt = 0; kt < 8; ++kt) {
        s16x8 a = *(const s16x8*)&h2[(size_t)arow * 256 + kt * 32 + quad * 8];
        s16x8 b = *(const s16x8*)&WuT[col][kt * 32 + quad * 8];
        acc = mfma16(a, b, acc);
    }
    float bvc = bu[col];
#pragma unroll
    for (int r = 0; r < 4; ++r) {
        int node = n0 + quad * 4 + r;
        if (node < N) {
            float v = obs[node] ? ((tl[node] == col) ? 0.0f : AZ) : (acc[r] + bvc);
            out[(size_t)node * 16 + col] = v;
        }
    }
}

// ---- launch ------------------------------------------------------------
extern "C" void kernel_launch(void* const* d_in, const int* in_sizes, int n_in,
                              void* d_out, int out_size, void* d_ws, size_t ws_size,
                              hipStream_t stream) {
    const float* features = (const float*)d_in[0];
    const int* parent_idx = (const int*)d_in[1];
    const int* child_idx  = (const int*)d_in[2];
    const int* label_obs  = (const int*)d_in[3];
    const int* true_lab   = (const int*)d_in[4];
    const float* W1 = (const float*)d_in[5];
    const float* b1 = (const float*)d_in[6];
    const float* W2 = (const float*)d_in[7];
    const float* b2 = (const float*)d_in[8];
    const float* Wu = (const float*)d_in[9];
    const float* bu = (const float*)d_in[10];
    const float* We = (const float*)d_in[11];
    const float* be = (const float*)d_in[12];
    float* out = (float*)d_out;

    const int N = 100000, E = N - 1;

    // workspace layout (~103.6 MB): h1, h2 (bf16 N x 256), bf16-T weights, edge meta
    char* ws = (char*)d_ws;
    unsigned short* h1  = (unsigned short*)ws;
    unsigned short* h2  = (unsigned short*)(ws + (size_t)N * 256 * 2);
    unsigned short* W1T = (unsigned short*)(ws + (size_t)N * 256 * 4);
    unsigned short* W2T = W1T + 768 * 256;
    unsigned short* WeT = W2T + 256 * 256;
    int*            meta = (int*)(WeT + 512 * 256);

    transpose_cvt<<<768, 256, 0, stream>>>(W1, W1T, 768);
    transpose_cvt<<<256, 256, 0, stream>>>(W2, W2T, 256);
    transpose_cvt<<<512, 256, 0, stream>>>(We, WeT, 512);
    edge_meta_kernel<<<(E + 255) / 256, 256, 0, stream>>>(parent_idx, child_idx,
                                                          true_lab, label_obs, meta, E);

    // grid.x = column-block (2) fastest so both col-blocks of a row-tile are
    // co-resident -> A tile read once from HBM, 2nd read hits L2/L3.
    dim3 gn(2, (N + 127) / 128);
    gemm_kernel<0, 0><<<gn, 256, 0, stream>>>(features, W1T, b1, h1, N, 768,
                                              nullptr, nullptr, nullptr);
    gemm_kernel<1, 0><<<gn, 256, 0, stream>>>(h1, W2T, b2, h2, N, 256,
                                              nullptr, nullptr, nullptr);
    unary_kernel<<<(N + 63) / 64, 256, 0, stream>>>(h2, Wu, bu, true_lab, label_obs, out, N);
    dim3 ge(2, (E + 127) / 128);
    gemm_kernel<2, 1><<<ge, 256, 0, stream>>>(h2, WeT, be, out + (size_t)N * 16, E, 512,
                                              parent_idx, child_idx, meta);
}

// Round 2
// 650.134 us; speedup vs baseline: 1.1988x; 1.1988x over previous
//
#include <hip/hip_runtime.h>
#include <cstddef>

#define AZ -999999.0f

typedef float  f32x4  __attribute__((ext_vector_type(4)));
typedef short  s16x8  __attribute__((ext_vector_type(8)));
typedef __bf16 bf16x8 __attribute__((ext_vector_type(8)));

__device__ __forceinline__ unsigned short f2bf(float f) {
    union { float f; unsigned u; } un; un.f = f;
    return (unsigned short)((un.u + 0x7FFFu + ((un.u >> 16) & 1u)) >> 16);
}

__device__ __forceinline__ f32x4 mfma16(s16x8 a, s16x8 b, f32x4 c) {
    return __builtin_amdgcn_mfma_f32_16x16x32_bf16(
        __builtin_bit_cast(bf16x8, a), __builtin_bit_cast(bf16x8, b), c, 0, 0, 0);
}

// async global->LDS, 16B per lane; LDS dest = wave-uniform base + lane*16
__device__ __forceinline__ void gl2lds16(const void* g, void* l) {
    __builtin_amdgcn_global_load_lds(
        (const __attribute__((address_space(1))) unsigned int*)g,
        (__attribute__((address_space(3))) unsigned int*)l, 16, 0, 0);
}

// ---- tiny setup kernels ------------------------------------------------
// B (K x 256, f32 row-major)  ->  BT (256 x K, bf16 row-major)
__global__ void transpose_cvt(const float* __restrict__ B,
                              unsigned short* __restrict__ BT, int K) {
    int idx = blockIdx.x * 256 + threadIdx.x;   // grid.x == K exactly
    int k = idx >> 8, n = idx & 255;
    BT[(size_t)n * K + k] = f2bf(B[idx]);
}

// per-edge packed mask metadata: pl | cl<<4 | op<<8 | oc<<9
__global__ void edge_meta_kernel(const int* __restrict__ pidx, const int* __restrict__ cidx,
                                 const int* __restrict__ tl, const int* __restrict__ obs,
                                 int* __restrict__ meta, int E) {
    int e = blockIdx.x * 256 + threadIdx.x;
    if (e < E) {
        int p = pidx[e], c = cidx[e];
        meta[e] = (tl[p] & 15) | ((tl[c] & 15) << 4) | ((obs[p] & 1) << 8) | ((obs[c] & 1) << 9);
    }
}

// ---- main GEMM (m97 structure: global_load_lds staging, 2-barrier K loop)
// AMODE: 0 = A f32 row-major lda=K (features; cvt->bf16 at frag read)
//        1 = A bf16 row-major lda=K
//        2 = A bf16 gathered: rows = h2[parent] (k<256) | h2[child] (k>=256), lda=256
// EPI:   0 = relu(acc+bias) -> bf16, ldc=256
//        1 = edge mask (meta) on acc+bias -> f32, ldc=256
template<int AMODE, int EPI>
__global__ __launch_bounds__(256) void gemm_kernel(
    const void* __restrict__ Aptr, const unsigned short* __restrict__ BT,
    const float* __restrict__ bias, void* __restrict__ outp,
    int M, int K,
    const int* __restrict__ parent_idx, const int* __restrict__ child_idx,
    const int* __restrict__ meta)
{
    constexpr int ABYTES = (AMODE == 0) ? 16384 : 8192;   // 128x32 f32 or bf16
    __shared__ __align__(16) char smem[ABYTES + 8192];
    float*          Asf = (float*)smem;
    unsigned short* Ash = (unsigned short*)smem;
    unsigned short* Bsh = (unsigned short*)(smem + ABYTES);

    const int tid  = threadIdx.x;
    const int lane = tid & 63, wave = tid >> 6;
    const int row0    = blockIdx.y * 128;
    const int colbase = blockIdx.x * 128;
    const int wr = (wave >> 1) * 64, wc = (wave & 1) * 64;
    const int quad = lane >> 4, l16 = lane & 15;

    // ---- staging geometry (prologue-computed offsets) ----
    // B tile (all modes): bf16 128x32, 2 calls/wave, 16 rows/call
    const int sub4 = lane >> 2, c4 = lane & 3;
    const int gcB  = c4 ^ ((sub4 >> 1) & 3);            // XOR swizzle: (row>>1)&3
    size_t b_off[2]; unsigned lds_b[2];
#pragma unroll
    for (int j = 0; j < 2; ++j) {
        int r = wave * 32 + j * 16 + sub4;
        b_off[j] = (size_t)(colbase + r) * K + gcB * 8;
        lds_b[j] = (unsigned)(wave * 32 + j * 16) * 64; // bytes
    }
    // A tile
    const int sub8 = lane >> 3, c8 = lane & 7;
    size_t a_off[4]; unsigned lds_a[4];
    int pn[2], cn[2];
    if constexpr (AMODE == 0) {
        const int gcA = c8 ^ sub8;                      // f32: swizzle by row&7
#pragma unroll
        for (int j = 0; j < 4; ++j) {
            int r  = wave * 32 + j * 8 + sub8;
            int gr = row0 + r; if (gr > M - 1) gr = M - 1;
            a_off[j] = (size_t)gr * K + gcA * 4;        // float elements
            lds_a[j] = (unsigned)(wave * 32 + j * 8) * 128;
        }
    } else {
        const int gcA = c4 ^ ((sub4 >> 1) & 3);
#pragma unroll
        for (int j = 0; j < 2; ++j) {
            int r  = wave * 32 + j * 16 + sub4;
            int gr = row0 + r; if (gr > M - 1) gr = M - 1;
            if constexpr (AMODE == 2) { pn[j] = parent_idx[gr]; cn[j] = child_idx[gr]; }
            a_off[j] = (size_t)gr * K + gcA * 8;        // ushort elements
            lds_a[j] = (unsigned)(wave * 32 + j * 16) * 64;
        }
        if constexpr (AMODE == 2) { a_off[0] = gcA * 8; a_off[1] = gcA * 8; }
    }

    const f32x4 fz = {0.f, 0.f, 0.f, 0.f};
    f32x4 acc[4][4];
#pragma unroll
    for (int i = 0; i < 4; ++i)
#pragma unroll
        for (int j = 0; j < 4; ++j) acc[i][j] = fz;

    const unsigned short* Abh = (const unsigned short*)Aptr;
    const float*          Af  = (const float*)Aptr;

    const int nkt = K >> 5;
    for (int kt = 0; kt < nkt; ++kt) {
        const int kbase = kt << 5;
        // ---- issue async staging (LDS free: barrier at end of prev iter) ----
        if constexpr (AMODE == 0) {
#pragma unroll
            for (int j = 0; j < 4; ++j)
                gl2lds16(Af + a_off[j] + kbase, smem + lds_a[j]);
        } else if constexpr (AMODE == 1) {
#pragma unroll
            for (int j = 0; j < 2; ++j)
                gl2lds16(Abh + a_off[j] + kbase, smem + lds_a[j]);
        } else {
#pragma unroll
            for (int j = 0; j < 2; ++j) {
                int node = (kbase < 256) ? pn[j] : cn[j];
                gl2lds16(Abh + (size_t)node * 256 + (kbase & 255) + a_off[j],
                         smem + lds_a[j]);
            }
        }
#pragma unroll
        for (int j = 0; j < 2; ++j)
            gl2lds16(BT + b_off[j] + kbase, (char*)Bsh + lds_b[j]);

        __syncthreads();   // drains vmcnt(0): tiles resident

        // ---- fragment reads (swizzled) + MFMA ----
        s16x8 af[4], bf[4];
        if constexpr (AMODE == 0) {
            const int s = l16 & 7;
            const int c0 = (2 * quad) ^ s, c1 = c0 ^ 1;
#pragma unroll
            for (int f = 0; f < 4; ++f) {
                int row = wr + f * 16 + l16;
                f32x4 v0 = *(const f32x4*)&Asf[row * 32 + c0 * 4];
                f32x4 v1 = *(const f32x4*)&Asf[row * 32 + c1 * 4];
                s16x8 a;
                a[0] = (short)f2bf(v0[0]); a[1] = (short)f2bf(v0[1]);
                a[2] = (short)f2bf(v0[2]); a[3] = (short)f2bf(v0[3]);
                a[4] = (short)f2bf(v1[0]); a[5] = (short)f2bf(v1[1]);
                a[6] = (short)f2bf(v1[2]); a[7] = (short)f2bf(v1[3]);
                af[f] = a;
            }
        } else {
            const int ca = quad ^ ((l16 >> 1) & 3);
#pragma unroll
            for (int f = 0; f < 4; ++f)
                af[f] = *(const s16x8*)&Ash[(wr + f * 16 + l16) * 32 + ca * 8];
        }
        {
            const int cb = quad ^ ((l16 >> 1) & 3);
#pragma unroll
            for (int f = 0; f < 4; ++f)
                bf[f] = *(const s16x8*)&Bsh[(wc + f * 16 + l16) * 32 + cb * 8];
        }
#pragma unroll
        for (int fr = 0; fr < 4; ++fr)
#pragma unroll
            for (int fc = 0; fc < 4; ++fc)
                acc[fr][fc] = mfma16(af[fr], bf[fc], acc[fr][fc]);
        __syncthreads();   // all waves done reading LDS before next-iter DMA
    }

    // ---- epilogue. C/D layout (measured): col = lane&15, row = quad*4 + reg
    float bv[4];
#pragma unroll
    for (int fc = 0; fc < 4; ++fc) bv[fc] = bias[colbase + wc + fc * 16 + l16];

    if constexpr (EPI == 0) {
        unsigned short* out = (unsigned short*)outp;
#pragma unroll
        for (int fr = 0; fr < 4; ++fr) {
#pragma unroll
            for (int r = 0; r < 4; ++r) {
                int gr = row0 + wr + fr * 16 + quad * 4 + r;
                if (gr < M) {
#pragma unroll
                    for (int fc = 0; fc < 4; ++fc) {
                        float v = acc[fr][fc][r] + bv[fc];
                        v = v > 0.f ? v : 0.f;
                        out[(size_t)gr * 256 + colbase + wc + fc * 16 + l16] = f2bf(v);
                    }
                }
            }
        }
    } else {
        float* out = (float*)outp;
#pragma unroll
        for (int fr = 0; fr < 4; ++fr) {
#pragma unroll
            for (int r = 0; r < 4; ++r) {
                int e = row0 + wr + fr * 16 + quad * 4 + r;
                if (e < M) {
                    int m  = meta[e];
                    int pl = m & 15, cl = (m >> 4) & 15;
                    int op = (m >> 8) & 1, oc = (m >> 9) & 1;
#pragma unroll
                    for (int fc = 0; fc < 4; ++fc) {
                        int n = colbase + wc + fc * 16 + l16;
                        float v = acc[fr][fc][r] + bv[fc];
                        int rr = n >> 4, cc = n & 15;
                        if (op & oc)  v = (rr == pl && cc == cl) ? 0.0f : AZ;
                        else if (oc)  { if (rr != cl) v += AZ; }
                        else if (op)  { if (cc != pl) v += AZ; }
                        out[(size_t)e * 256 + n] = v;
                    }
                }
            }
        }
    }
}

// ---- unary: 16 nodes per wave via one MFMA column-tile -----------------
__global__ __launch_bounds__(256) void unary_kernel(
    const unsigned short* __restrict__ h2, const float* __restrict__ Wu,
    const float* __restrict__ bu, const int* __restrict__ tl,
    const int* __restrict__ obs, float* __restrict__ out, int N)
{
    __shared__ unsigned short WuT[16][272];
    const int tid = threadIdx.x;
    {
        const f32x4* wrow = (const f32x4*)&Wu[tid * 16];
        float tmp[16];
#pragma unroll
        for (int j = 0; j < 4; ++j) {
            f32x4 v = wrow[j];
            tmp[j * 4 + 0] = v[0]; tmp[j * 4 + 1] = v[1];
            tmp[j * 4 + 2] = v[2]; tmp[j * 4 + 3] = v[3];
        }
#pragma unroll
        for (int c = 0; c < 16; ++c) WuT[c][tid] = f2bf(tmp[c]);
    }
    __syncthreads();
    const int lane = tid & 63, wave = tid >> 6;
    const int quad = lane >> 4, col = lane & 15;
    const int n0 = blockIdx.x * 64 + wave * 16;
    int arow = n0 + col;
    if (arow > N - 1) arow = N - 1;
    f32x4 acc = {0.f, 0.f, 0.f, 0.f};
#pragma unroll
    for (int kt = 0; kt < 8; ++kt) {
        s16x8 a = *(const s16x8*)&h2[(size_t)arow * 256 + kt * 32 + quad * 8];
        s16x8 b = *(const s16x8*)&WuT[col][kt * 32 + quad * 8];
        acc = mfma16(a, b, acc);
    }
    float bvc = bu[col];
#pragma unroll
    for (int r = 0; r < 4; ++r) {
        int node = n0 + quad * 4 + r;
        if (node < N) {
            float v = obs[node] ? ((tl[node] == col) ? 0.0f : AZ) : (acc[r] + bvc);
            out[(size_t)node * 16 + col] = v;
        }
    }
}

// ---- launch ------------------------------------------------------------
extern "C" void kernel_launch(void* const* d_in, const int* in_sizes, int n_in,
                              void* d_out, int out_size, void* d_ws, size_t ws_size,
                              hipStream_t stream) {
    const float* features = (const float*)d_in[0];
    const int* parent_idx = (const int*)d_in[1];
    const int* child_idx  = (const int*)d_in[2];
    const int* label_obs  = (const int*)d_in[3];
    const int* true_lab   = (const int*)d_in[4];
    const float* W1 = (const float*)d_in[5];
    const float* b1 = (const float*)d_in[6];
    const float* W2 = (const float*)d_in[7];
    const float* b2 = (const float*)d_in[8];
    const float* Wu = (const float*)d_in[9];
    const float* bu = (const float*)d_in[10];
    const float* We = (const float*)d_in[11];
    const float* be = (const float*)d_in[12];
    float* out = (float*)d_out;

    const int N = 100000, E = N - 1;

    // workspace (~104 MB): h1, h2 (bf16 N x 256), bf16-T weights, edge meta
    char* ws = (char*)d_ws;
    unsigned short* h1  = (unsigned short*)ws;
    unsigned short* h2  = (unsigned short*)(ws + (size_t)N * 256 * 2);
    unsigned short* W1T = (unsigned short*)(ws + (size_t)N * 256 * 4);
    unsigned short* W2T = W1T + 768 * 256;
    unsigned short* WeT = W2T + 256 * 256;
    int*            meta = (int*)(WeT + 512 * 256);

    transpose_cvt<<<768, 256, 0, stream>>>(W1, W1T, 768);
    transpose_cvt<<<256, 256, 0, stream>>>(W2, W2T, 256);
    transpose_cvt<<<512, 256, 0, stream>>>(We, WeT, 512);
    edge_meta_kernel<<<(E + 255) / 256, 256, 0, stream>>>(parent_idx, child_idx,
                                                          true_lab, label_obs, meta, E);

    // grid.x = column-block fastest: both col-blocks of a row-tile co-resident
    dim3 gn(2, (N + 127) / 128);
    gemm_kernel<0, 0><<<gn, 256, 0, stream>>>(features, W1T, b1, h1, N, 768,
                                              nullptr, nullptr, nullptr);
    gemm_kernel<1, 0><<<gn, 256, 0, stream>>>(h1, W2T, b2, h2, N, 256,
                                              nullptr, nullptr, nullptr);
    unary_kernel<<<(N + 63) / 64, 256, 0, stream>>>(h2, Wu, bu, true_lab, label_obs, out, N);
    dim3 ge(2, (E + 127) / 128);
    gemm_kernel<2, 1><<<ge, 256, 0, stream>>>(h2, WeT, be, out + (size_t)N * 16, E, 512,
                                              parent_idx, child_idx, meta);
}

// Round 3
// 640.153 us; speedup vs baseline: 1.2174x; 1.0156x over previous
//
#include <hip/hip_runtime.h>
#include <cstddef>

#define AZ -999999.0f

typedef float  f32x4  __attribute__((ext_vector_type(4)));
typedef short  s16x8  __attribute__((ext_vector_type(8)));
typedef __bf16 bf16x8 __attribute__((ext_vector_type(8)));
typedef unsigned short ushort_t;

__device__ __forceinline__ unsigned short f2bf(float f) {
    union { float f; unsigned u; } un; un.f = f;
    return (unsigned short)((un.u + 0x7FFFu + ((un.u >> 16) & 1u)) >> 16);
}

__device__ __forceinline__ f32x4 mfma16(s16x8 a, s16x8 b, f32x4 c) {
    return __builtin_amdgcn_mfma_f32_16x16x32_bf16(
        __builtin_bit_cast(bf16x8, a), __builtin_bit_cast(bf16x8, b), c, 0, 0, 0);
}

// async global->LDS, 16B per lane; LDS dest = wave-uniform base + lane*16
__device__ __forceinline__ void gl2lds16(const void* g, void* l) {
    __builtin_amdgcn_global_load_lds(
        (const __attribute__((address_space(1))) unsigned int*)g,
        (__attribute__((address_space(3))) unsigned int*)l, 16, 0, 0);
}

// ---- combined setup: weight transposes+casts, Wu swizzle, edge meta ----
// blocks [0,768): W1T   [768,1024): W2T   [1024,1536): WeT
// [1536,1552): WuTs (pre-swizzled)   [1552,1943): meta
__global__ void setup_kernel(
    const float* __restrict__ W1, const float* __restrict__ W2,
    const float* __restrict__ We, const float* __restrict__ Wu,
    ushort_t* __restrict__ W1T, ushort_t* __restrict__ W2T,
    ushort_t* __restrict__ WeT, ushort_t* __restrict__ WuTs,
    const int* __restrict__ pidx, const int* __restrict__ cidx,
    const int* __restrict__ tl, const int* __restrict__ obs,
    int* __restrict__ meta, int E)
{
    int b = blockIdx.x, t = threadIdx.x;
    if (b < 768) {
        int idx = b * 256 + t; int k = idx >> 8, n = idx & 255;
        W1T[(size_t)n * 768 + k] = f2bf(W1[idx]);
    } else if (b < 1024) {
        int idx = (b - 768) * 256 + t; int k = idx >> 8, n = idx & 255;
        W2T[n * 256 + k] = f2bf(W2[idx]);
    } else if (b < 1536) {
        int idx = (b - 1024) * 256 + t; int k = idx >> 8, n = idx & 255;
        WeT[(size_t)n * 512 + k] = f2bf(We[idx]);
    } else if (b < 1552) {
        int idx = (b - 1536) * 256 + t; int k = idx >> 4, c = idx & 15;
        // WuT[c][k], stored with chunk swizzle: chunk' = (k>>3) ^ (c&7)
        WuTs[c * 256 + (((k >> 3) ^ (c & 7)) << 3) + (k & 7)] = f2bf(Wu[idx]);
    } else {
        int e = (b - 1552) * 256 + t;
        if (e < E) {
            int p = pidx[e], c = cidx[e];
            meta[e] = (tl[p] & 15) | ((tl[c] & 15) << 4)
                    | ((obs[p] & 1) << 8) | ((obs[c] & 1) << 9);
        }
    }
}

// ---- main GEMM (m97 structure). Used for GEMM1 (AMODE 0) and edge (AMODE 2)
template<int AMODE, int EPI>
__global__ __launch_bounds__(256) void gemm_kernel(
    const void* __restrict__ Aptr, const ushort_t* __restrict__ BT,
    const float* __restrict__ bias, void* __restrict__ outp,
    int M, int K,
    const int* __restrict__ parent_idx, const int* __restrict__ child_idx,
    const int* __restrict__ meta)
{
    constexpr int ABYTES = (AMODE == 0) ? 16384 : 8192;   // 128x32 f32 or bf16
    __shared__ __align__(16) char smem[ABYTES + 8192];
    float*    Asf = (float*)smem;
    ushort_t* Ash = (ushort_t*)smem;
    ushort_t* Bsh = (ushort_t*)(smem + ABYTES);

    const int tid  = threadIdx.x;
    const int lane = tid & 63, wave = tid >> 6;
    const int row0    = blockIdx.y * 128;
    const int colbase = blockIdx.x * 128;
    const int wr = (wave >> 1) * 64, wc = (wave & 1) * 64;
    const int quad = lane >> 4, l16 = lane & 15;

    const int sub4 = lane >> 2, c4 = lane & 3;
    const int gcB  = c4 ^ ((sub4 >> 1) & 3);
    size_t b_off[2]; unsigned lds_b[2];
#pragma unroll
    for (int j = 0; j < 2; ++j) {
        int r = wave * 32 + j * 16 + sub4;
        b_off[j] = (size_t)(colbase + r) * K + gcB * 8;
        lds_b[j] = (unsigned)(wave * 32 + j * 16) * 64;
    }
    const int sub8 = lane >> 3, c8 = lane & 7;
    size_t a_off[4]; unsigned lds_a[4];
    int pn[2], cn[2];
    if constexpr (AMODE == 0) {
        const int gcA = c8 ^ sub8;
#pragma unroll
        for (int j = 0; j < 4; ++j) {
            int r  = wave * 32 + j * 8 + sub8;
            int gr = row0 + r; if (gr > M - 1) gr = M - 1;
            a_off[j] = (size_t)gr * K + gcA * 4;
            lds_a[j] = (unsigned)(wave * 32 + j * 8) * 128;
        }
    } else {
        const int gcA = c4 ^ ((sub4 >> 1) & 3);
#pragma unroll
        for (int j = 0; j < 2; ++j) {
            int r  = wave * 32 + j * 16 + sub4;
            int gr = row0 + r; if (gr > M - 1) gr = M - 1;
            if constexpr (AMODE == 2) { pn[j] = parent_idx[gr]; cn[j] = child_idx[gr]; }
            a_off[j] = (size_t)gr * K + gcA * 8;
            lds_a[j] = (unsigned)(wave * 32 + j * 16) * 64;
        }
        if constexpr (AMODE == 2) { a_off[0] = gcA * 8; a_off[1] = gcA * 8; }
    }

    const f32x4 fz = {0.f, 0.f, 0.f, 0.f};
    f32x4 acc[4][4];
#pragma unroll
    for (int i = 0; i < 4; ++i)
#pragma unroll
        for (int j = 0; j < 4; ++j) acc[i][j] = fz;

    const ushort_t* Abh = (const ushort_t*)Aptr;
    const float*    Af  = (const float*)Aptr;

    const int nkt = K >> 5;
    for (int kt = 0; kt < nkt; ++kt) {
        const int kbase = kt << 5;
        if constexpr (AMODE == 0) {
#pragma unroll
            for (int j = 0; j < 4; ++j)
                gl2lds16(Af + a_off[j] + kbase, smem + lds_a[j]);
        } else {
#pragma unroll
            for (int j = 0; j < 2; ++j) {
                int node = (kbase < 256) ? pn[j] : cn[j];
                gl2lds16(Abh + (size_t)node * 256 + (kbase & 255) + a_off[j],
                         smem + lds_a[j]);
            }
        }
#pragma unroll
        for (int j = 0; j < 2; ++j)
            gl2lds16(BT + b_off[j] + kbase, (char*)Bsh + lds_b[j]);

        __syncthreads();

        s16x8 af[4], bf[4];
        if constexpr (AMODE == 0) {
            const int s = l16 & 7;
            const int c0 = (2 * quad) ^ s, c1 = c0 ^ 1;
#pragma unroll
            for (int f = 0; f < 4; ++f) {
                int row = wr + f * 16 + l16;
                f32x4 v0 = *(const f32x4*)&Asf[row * 32 + c0 * 4];
                f32x4 v1 = *(const f32x4*)&Asf[row * 32 + c1 * 4];
                s16x8 a;
                a[0] = (short)f2bf(v0[0]); a[1] = (short)f2bf(v0[1]);
                a[2] = (short)f2bf(v0[2]); a[3] = (short)f2bf(v0[3]);
                a[4] = (short)f2bf(v1[0]); a[5] = (short)f2bf(v1[1]);
                a[6] = (short)f2bf(v1[2]); a[7] = (short)f2bf(v1[3]);
                af[f] = a;
            }
        } else {
            const int ca = quad ^ ((l16 >> 1) & 3);
#pragma unroll
            for (int f = 0; f < 4; ++f)
                af[f] = *(const s16x8*)&Ash[(wr + f * 16 + l16) * 32 + ca * 8];
        }
        {
            const int cb = quad ^ ((l16 >> 1) & 3);
#pragma unroll
            for (int f = 0; f < 4; ++f)
                bf[f] = *(const s16x8*)&Bsh[(wc + f * 16 + l16) * 32 + cb * 8];
        }
#pragma unroll
        for (int fr = 0; fr < 4; ++fr)
#pragma unroll
            for (int fc = 0; fc < 4; ++fc)
                acc[fr][fc] = mfma16(af[fr], bf[fc], acc[fr][fc]);
        __syncthreads();
    }

    float bv[4];
#pragma unroll
    for (int fc = 0; fc < 4; ++fc) bv[fc] = bias[colbase + wc + fc * 16 + l16];

    if constexpr (EPI == 0) {
        ushort_t* out = (ushort_t*)outp;
#pragma unroll
        for (int fr = 0; fr < 4; ++fr) {
#pragma unroll
            for (int r = 0; r < 4; ++r) {
                int gr = row0 + wr + fr * 16 + quad * 4 + r;
                if (gr < M) {
#pragma unroll
                    for (int fc = 0; fc < 4; ++fc) {
                        float v = acc[fr][fc][r] + bv[fc];
                        v = v > 0.f ? v : 0.f;
                        out[(size_t)gr * 256 + colbase + wc + fc * 16 + l16] = f2bf(v);
                    }
                }
            }
        }
    } else {
        float* out = (float*)outp;
#pragma unroll
        for (int fr = 0; fr < 4; ++fr) {
#pragma unroll
            for (int r = 0; r < 4; ++r) {
                int e = row0 + wr + fr * 16 + quad * 4 + r;
                if (e < M) {
                    int m  = meta[e];
                    int pl = m & 15, cl = (m >> 4) & 15;
                    int op = (m >> 8) & 1, oc = (m >> 9) & 1;
#pragma unroll
                    for (int fc = 0; fc < 4; ++fc) {
                        int n = colbase + wc + fc * 16 + l16;
                        float v = acc[fr][fc][r] + bv[fc];
                        int rr = n >> 4, cc = n & 15;
                        if (op & oc)  v = (rr == pl && cc == cl) ? 0.0f : AZ;
                        else if (oc)  { if (rr != cl) v += AZ; }
                        else if (op)  { if (cc != pl) v += AZ; }
                        out[(size_t)e * 256 + n] = v;
                    }
                }
            }
        }
    }
}

// ---- fused GEMM2 + unary: 64 rows x 256 cols per block ------------------
// phase A: h2 = relu(h1 @ W2T + b2) into C-layout regs
// phase B: h2 tile -> swizzled LDS (bf16)
// phase C: h2 global write (vectorized from LDS) + unary MFMA + mask + store
__global__ __launch_bounds__(256) void gemm2_unary_kernel(
    const ushort_t* __restrict__ h1, const ushort_t* __restrict__ W2T,
    const float* __restrict__ b2, const ushort_t* __restrict__ WuTs,
    const float* __restrict__ bu, const int* __restrict__ tl,
    const int* __restrict__ obs, ushort_t* __restrict__ h2,
    float* __restrict__ out_unary, int N)
{
    __shared__ __align__(16) char smem[4096 + 16384 + 32768 + 8192];
    ushort_t* Ash = (ushort_t*)smem;               // 64 x 32
    ushort_t* Bsh = (ushort_t*)(smem + 4096);      // 256 x 32
    ushort_t* Hsh = (ushort_t*)(smem + 20480);     // 64 x 256 (chunk-swizzled)
    ushort_t* Wsh = (ushort_t*)(smem + 53248);     // 16 x 256 (pre-swizzled)

    const int tid = threadIdx.x, lane = tid & 63, wave = tid >> 6;
    const int quad = lane >> 4, l16 = lane & 15;
    const int sub4 = lane >> 2, c4 = lane & 3;
    const int n0 = blockIdx.x * 64;
    const int wc = wave * 64;

    // stage WuT (8KB, pre-swizzled in global): 2 rounds
#pragma unroll
    for (int j = 0; j < 2; ++j)
        gl2lds16(WuTs + j * 2048 + wave * 512 + lane * 8,
                 (char*)Wsh + j * 4096 + wave * 1024);

    // staging geometry
    const int gcA = c4 ^ ((sub4 >> 1) & 3);
    int gra = n0 + wave * 16 + sub4; if (gra > N - 1) gra = N - 1;
    const size_t a_goff = (size_t)gra * 256 + gcA * 8;
    const unsigned a_loff = (unsigned)wave * 1024;
    size_t b_goff[4]; unsigned b_loff[4];
#pragma unroll
    for (int j = 0; j < 4; ++j) {
        int nrow = j * 64 + wave * 16 + sub4;
        b_goff[j] = (size_t)nrow * 256 + gcA * 8;
        b_loff[j] = (unsigned)(j * 64 + wave * 16) * 64;
    }

    const f32x4 fz = {0.f, 0.f, 0.f, 0.f};
    f32x4 acc[4][4];
#pragma unroll
    for (int i = 0; i < 4; ++i)
#pragma unroll
        for (int j = 0; j < 4; ++j) acc[i][j] = fz;

    // ---- phase A: K = 256 ----
    for (int kt = 0; kt < 8; ++kt) {
        const int kbase = kt << 5;
        gl2lds16(h1 + a_goff + kbase, smem + a_loff);
#pragma unroll
        for (int j = 0; j < 4; ++j)
            gl2lds16(W2T + b_goff[j] + kbase, (char*)Bsh + b_loff[j]);
        __syncthreads();
        const int cs = quad ^ ((l16 >> 1) & 3);
        s16x8 af[4], bf[4];
#pragma unroll
        for (int f = 0; f < 4; ++f)
            af[f] = *(const s16x8*)&Ash[(f * 16 + l16) * 32 + cs * 8];
#pragma unroll
        for (int f = 0; f < 4; ++f)
            bf[f] = *(const s16x8*)&Bsh[(wc + f * 16 + l16) * 32 + cs * 8];
#pragma unroll
        for (int fr = 0; fr < 4; ++fr)
#pragma unroll
            for (int fc = 0; fc < 4; ++fc)
                acc[fr][fc] = mfma16(af[fr], bf[fc], acc[fr][fc]);
        __syncthreads();
    }

    // ---- phase B: relu+bias -> swizzled LDS ----
    float bv[4];
#pragma unroll
    for (int fc = 0; fc < 4; ++fc) bv[fc] = b2[wc + fc * 16 + l16];
#pragma unroll
    for (int fr = 0; fr < 4; ++fr) {
#pragma unroll
        for (int r = 0; r < 4; ++r) {
            int row = fr * 16 + quad * 4 + r;
#pragma unroll
            for (int fc = 0; fc < 4; ++fc) {
                int col = wc + fc * 16 + l16;
                float v = acc[fr][fc][r] + bv[fc];
                v = v > 0.f ? v : 0.f;
                Hsh[row * 256 + (((col >> 3) ^ (row & 7)) << 3) + (col & 7)] = f2bf(v);
            }
        }
    }
    __syncthreads();

    // ---- phase C1: h2 global write, vectorized+de-swizzled from LDS ----
    {
        int row = tid >> 2, cc = tid & 3;
        int gr = n0 + row;
        if (gr < N) {
#pragma unroll
            for (int j = 0; j < 8; ++j) {
                int phys = (j * 4 + cc) ^ (row & 7);
                s16x8 v = *(const s16x8*)&Hsh[row * 256 + phys * 8];
                *(s16x8*)&h2[(size_t)gr * 256 + (j * 4 + cc) * 8] = v;
            }
        }
    }

    // ---- phase C2: unary = h2_tile @ WuT, mask, store ----
    {
        const int arow = wave * 16 + l16;
        f32x4 accu = fz;
#pragma unroll
        for (int kt = 0; kt < 8; ++kt) {
            int pc = (kt * 4 + quad) ^ (l16 & 7);
            s16x8 a = *(const s16x8*)&Hsh[arow * 256 + pc * 8];
            s16x8 b = *(const s16x8*)&Wsh[l16 * 256 + pc * 8];
            accu = mfma16(a, b, accu);
        }
        float bvc = bu[l16];
#pragma unroll
        for (int r = 0; r < 4; ++r) {
            int node = n0 + wave * 16 + quad * 4 + r;
            if (node < N) {
                float v = obs[node] ? ((tl[node] == l16) ? 0.0f : AZ) : (accu[r] + bvc);
                out_unary[(size_t)node * 16 + l16] = v;
            }
        }
    }
}

// ---- launch ------------------------------------------------------------
extern "C" void kernel_launch(void* const* d_in, const int* in_sizes, int n_in,
                              void* d_out, int out_size, void* d_ws, size_t ws_size,
                              hipStream_t stream) {
    const float* features = (const float*)d_in[0];
    const int* parent_idx = (const int*)d_in[1];
    const int* child_idx  = (const int*)d_in[2];
    const int* label_obs  = (const int*)d_in[3];
    const int* true_lab   = (const int*)d_in[4];
    const float* W1 = (const float*)d_in[5];
    const float* b1 = (const float*)d_in[6];
    const float* W2 = (const float*)d_in[7];
    const float* b2 = (const float*)d_in[8];
    const float* Wu = (const float*)d_in[9];
    const float* bu = (const float*)d_in[10];
    const float* We = (const float*)d_in[11];
    const float* be = (const float*)d_in[12];
    float* out = (float*)d_out;

    const int N = 100000, E = N - 1;

    char* ws = (char*)d_ws;
    ushort_t* h1   = (ushort_t*)ws;
    ushort_t* h2   = (ushort_t*)(ws + (size_t)N * 256 * 2);
    ushort_t* W1T  = (ushort_t*)(ws + (size_t)N * 256 * 4);
    ushort_t* W2T  = W1T + 768 * 256;
    ushort_t* WeT  = W2T + 256 * 256;
    ushort_t* WuTs = WeT + 512 * 256;
    int*      meta = (int*)(WuTs + 16 * 256);

    setup_kernel<<<1943, 256, 0, stream>>>(W1, W2, We, Wu, W1T, W2T, WeT, WuTs,
                                           parent_idx, child_idx, true_lab, label_obs,
                                           meta, E);

    dim3 gn(2, (N + 127) / 128);
    gemm_kernel<0, 0><<<gn, 256, 0, stream>>>(features, W1T, b1, h1, N, 768,
                                              nullptr, nullptr, nullptr);
    gemm2_unary_kernel<<<(N + 63) / 64, 256, 0, stream>>>(h1, W2T, b2, WuTs, bu,
                                                          true_lab, label_obs, h2, out, N);
    dim3 ge(2, (E + 127) / 128);
    gemm_kernel<2, 1><<<ge, 256, 0, stream>>>(h2, WeT, be, out + (size_t)N * 16, E, 512,
                                              parent_idx, child_idx, meta);
}